// Round 1
// 43.843 us; speedup vs baseline: 1.3144x; 1.3144x over previous
//
#include <hip/hip_runtime.h>

// Problem constants (reference: B=4, L=8192, D=1024, K=7)
constexpr int B = 4;
constexpr int L = 8192;
constexpr int D = 1024;
constexpr int K = 7;
constexpr int HALF = K / 2;   // 3
constexpr int T = 8;          // l-positions per block tile
constexpr int W = T + K - 1;  // 14 float4 window loads per thread
constexpr int NXCD = 8;

typedef float v4f __attribute__((ext_vector_type(4)));

// Block = 256 threads x v4f = all D=1024 channels, T consecutive l.
// Changes vs previous version:
//  1. NO LDS / NO __syncthreads: the segment mask is block-uniform, so every
//     thread computes all T masks from 14 uniform sb loads (sliding box sum).
//     This removes the s_waitcnt vmcnt(0) drain hipcc emits before s_barrier,
//     letting the compiler overlap the X-load tail with early FMAs/stores.
//  2. XCD-chunked bijective blockIdx swizzle (nwg=4096, %8==0): consecutive
//     tiles (which share a 6-row halo) land on the same XCD's L2.
__global__ __launch_bounds__(256, 4)
void dynconv_kernel(const float* __restrict__ x,
                    const float* __restrict__ sb,
                    const float* __restrict__ w,
                    const float* __restrict__ bias,
                    float* __restrict__ out)
{
    // ---- XCD-chunked swizzle (bijective since 4096 % 8 == 0) ----
    constexpr int nwg = B * (L / T);        // 4096
    constexpr int cpx = nwg / NXCD;         // 512 tiles per XCD chunk
    const int bid  = blockIdx.x;
    const int tile = (bid % NXCD) * cpx + bid / NXCD;

    const int nt  = L / T;                  // tiles per batch = 1024
    const int b   = tile / nt;
    const int l0  = (tile % nt) * T;
    const int tid = threadIdx.x;
    const int d0  = tid * 4;

    // ---- window loads first: x[b, l0-6 .. l0+T-1, d0:d0+4], all independent ----
    const float* xb = x + (size_t)b * L * D + d0;
    v4f X[W];
    #pragma unroll
    for (int j = 0; j < W; ++j) {
        const int l = l0 - (K - 1) + j;     // uniform condition per j
        X[j] = (l >= 0) ? *(const v4f*)(xb + (size_t)l * D)
                        : (v4f)(0.f);
    }

    // ---- weights: 28 contiguous floats per thread (4 channels x K) ----
    union { v4f q[7]; float f[28]; } wu;
    {
        const v4f* wp = (const v4f*)(w + (size_t)d0 * K); // 112B-aligned
        #pragma unroll
        for (int j = 0; j < 7; ++j) wu.q[j] = wp[j];
    }
    const v4f bv = *(const v4f*)(bias + d0);

    // ---- block-uniform mask: box-filter(boundaries, width 7), 0.5**count ----
    // All addresses depend only on (b, l0) -> uniform; sb is 128 KB, L2-hot.
    const float* sbb = sb + (size_t)b * L;
    float s[T + 2 * HALF];                  // positions l0-3 .. l0+10
    #pragma unroll
    for (int j = 0; j < T + 2 * HALF; ++j) {
        const int p = l0 - HALF + j;        // uniform condition per j
        s[j] = (p >= 0 && p < L) ? sbb[p] : 0.f;
    }
    float mask[T];
    {
        float c = 0.f;
        #pragma unroll
        for (int j = 0; j < K; ++j) c += s[j];
        mask[0] = exp2f(-c);
        #pragma unroll
        for (int t = 1; t < T; ++t) {
            c += s[t + K - 1] - s[t - 1];   // sliding box sum: 2 adds/step
            mask[t] = exp2f(-c);
        }
    }

    // ---- compute + streaming stores ----
    float* ob = out + ((size_t)b * L + (size_t)l0) * D + d0;
    #pragma unroll
    for (int t = 0; t < T; ++t) {
        v4f acc = bv;
        #pragma unroll
        for (int k = 0; k < K; ++k) {
            // wv[k][c] = w[(d0+c)*K + k] = wu.f[c*7 + k]
            v4f wk = { wu.f[0 * K + k], wu.f[1 * K + k],
                       wu.f[2 * K + k], wu.f[3 * K + k] };
            acc += wk * X[t + k];
        }
        acc *= mask[t];
        __builtin_nontemporal_store(acc, (v4f*)(ob + (size_t)t * D));
    }
}

extern "C" void kernel_launch(void* const* d_in, const int* in_sizes, int n_in,
                              void* d_out, int out_size, void* d_ws, size_t ws_size,
                              hipStream_t stream)
{
    const float* x    = (const float*)d_in[0];  // (B, L, D)
    const float* sb   = (const float*)d_in[1];  // (B, L)
    const float* w    = (const float*)d_in[2];  // (D, 1, K)
    const float* bias = (const float*)d_in[3];  // (D,)
    float* out = (float*)d_out;                 // (B, L, D)

    const int blocks = B * (L / T);             // 4096
    dynconv_kernel<<<blocks, 256, 0, stream>>>(x, sb, w, bias, out);
}